// Round 2
// baseline (471.439 us; speedup 1.0000x reference)
//
#include <hip/hip_runtime.h>
#include <stdint.h>
#include <stddef.h>

#define VV 3
#define NN 4096
#define DD 512
#define CC 10

typedef unsigned short bf16_t;
typedef __attribute__((ext_vector_type(8))) short bf16x8;
typedef __attribute__((ext_vector_type(4))) float f32x4;
typedef __attribute__((ext_vector_type(4))) int i32x4;
typedef __attribute__((ext_vector_type(4))) unsigned short u16x4;

#define MFMA16 __builtin_amdgcn_mfma_f32_16x16x32_bf16

__device__ __forceinline__ float bf2f(bf16_t u) {
  union { unsigned u; float f; } c; c.u = ((unsigned)u) << 16; return c.f;
}
__device__ __forceinline__ bf16_t f2bf(float f) {
  union { float f; unsigned u; } c; c.f = f;
  unsigned r = (c.u + 0x7FFFu + ((c.u >> 16) & 1u)) >> 16;
  return (bf16_t)r;
}
__device__ __forceinline__ float splus(float x) {
  float ax = fabsf(x);
  return fmaxf(x, 0.0f) + log1pf(expf(-ax));
}

// ---------------- K1: A (f32, binary) -> bitmask + dinv = 1/sqrt(deg) -------
// ballot-based: fully coalesced scalar loads; ballot over column group `it`
// IS mask word `it` of the row.
__global__ __launch_bounds__(256) void k_mask(const float* __restrict__ A,
    unsigned long long* __restrict__ mask, float* __restrict__ dinv)
{
  int wid = blockIdx.x * 4 + (threadIdx.x >> 6);   // row id in [0, V*N)
  int lane = threadIdx.x & 63;
  const float* row = A + (size_t)wid * NN;
  unsigned long long myw = 0ull;
#pragma unroll 8
  for (int it = 0; it < 64; ++it) {
    float x = row[it * 64 + lane];
    unsigned long long b = __ballot(x != 0.0f);
    if (lane == it) myw = b;
  }
  mask[(size_t)wid * 64 + lane] = myw;
  int pc = __popcll(myw);
#pragma unroll
  for (int s = 32; s; s >>= 1) pc += __shfl_xor(pc, s);
  if (lane == 0) dinv[wid] = 1.0f / sqrtf((float)(pc + 1));  // deg = popcnt + 1 (the +I)
}

// ---------------- K2: Xs_t[v][d][j] = dinv_j * X[v][j][d] (bf16), X_bf ------
__global__ __launch_bounds__(256) void k_xpose(const float* __restrict__ X,
    const float* __restrict__ dinv, bf16_t* __restrict__ Xs_t, bf16_t* __restrict__ X_bf)
{
  __shared__ float tile[64][65];
  int v = blockIdx.z;
  int jb = blockIdx.x * 64, db = blockIdx.y * 64;
  int t = threadIdx.x;
  int tr = t >> 4, tc = (t & 15) * 4;
  const float* Xv = X + (size_t)v * NN * DD;
#pragma unroll
  for (int it = 0; it < 4; ++it) {
    int r = it * 16 + tr;
    int j = jb + r;
    float4 x = *(const float4*)(Xv + (size_t)j * DD + db + tc);
    u16x4 ob = { f2bf(x.x), f2bf(x.y), f2bf(x.z), f2bf(x.w) };
    *(u16x4*)(X_bf + (size_t)v * NN * DD + (size_t)j * DD + db + tc) = ob;
    float s = dinv[v * NN + j];
    tile[r][tc + 0] = x.x * s; tile[r][tc + 1] = x.y * s;
    tile[r][tc + 2] = x.z * s; tile[r][tc + 3] = x.w * s;
  }
  __syncthreads();
#pragma unroll
  for (int it = 0; it < 4; ++it) {
    int r = it * 16 + tr;     // d-local
    int d = db + r;
    u16x4 ob = { f2bf(tile[tc + 0][r]), f2bf(tile[tc + 1][r]),
                 f2bf(tile[tc + 2][r]), f2bf(tile[tc + 3][r]) };
    *(u16x4*)(Xs_t + (size_t)v * DD * NN + (size_t)d * NN + jb + tc) = ob;
  }
}

// ---------------- K4: merged weight prep ------------------------------------
// blocks [0,385): Wc_t = (W1@W2)^T (bf16, padded to 16 rows), bp = b1@W2
// blocks [385,391): Wm_t = W_mlp^T (bf16, padded to 16 rows)
__global__ __launch_bounds__(256) void k_w(const float* __restrict__ W1,
    const float* __restrict__ b1, const float* __restrict__ W2,
    const float* __restrict__ W_mlp,
    bf16_t* __restrict__ Wc_t, float* __restrict__ bp, bf16_t* __restrict__ Wm_t)
{
  int t = threadIdx.x;
  if (blockIdx.x < 385) {
    int wid = blockIdx.x * 4 + (t >> 6);
    int lane = t & 63;
    if (wid >= VV * 513) return;
    int v = wid / 513, dd2 = wid % 513;
    const float* w2 = W2 + (size_t)v * DD * CC;
    const float* src = (dd2 < DD) ? (W1 + ((size_t)v * DD + dd2) * DD) : (b1 + (size_t)v * DD);
    float acc[CC];
#pragma unroll
    for (int c = 0; c < CC; ++c) acc[c] = 0.f;
    for (int it = 0; it < 8; ++it) {
      int e = it * 64 + lane;
      float w = src[e];
      const float* w2r = w2 + (size_t)e * CC;
#pragma unroll
      for (int c = 0; c < CC; ++c) acc[c] += w * w2r[c];
    }
#pragma unroll
    for (int c = 0; c < CC; ++c) {
#pragma unroll
      for (int s = 32; s; s >>= 1) acc[c] += __shfl_xor(acc[c], s);
    }
    if (lane == 0) {
      if (dd2 < DD) {
#pragma unroll
        for (int c = 0; c < CC; ++c) Wc_t[((size_t)v * 16 + c) * DD + dd2] = f2bf(acc[c]);
#pragma unroll
        for (int c = CC; c < 16; ++c) Wc_t[((size_t)v * 16 + c) * DD + dd2] = 0;
      } else {
#pragma unroll
        for (int c = 0; c < CC; ++c) bp[v * CC + c] = acc[c];
      }
    }
  } else {
    int idx = (blockIdx.x - 385) * 256 + t;
    if (idx >= VV * DD) return;
    int v = idx / DD, d = idx % DD;
#pragma unroll
    for (int c = 0; c < CC; ++c)
      Wm_t[((size_t)v * 16 + c) * DD + d] = f2bf(W_mlp[((size_t)v * DD + d) * CC + c]);
#pragma unroll
    for (int c = CC; c < 16; ++c) Wm_t[((size_t)v * 16 + c) * DD + d] = 0;
  }
}

// ---------------- K3: H0 = Dinv (A+I) Dinv X  (bitmask-A bf16 MFMA GEMM) ----
// BM=64, BN=128 -> 768 blocks (exactly 3 per CU), 52KB LDS -> 3 blocks/CU.
// A expansion: magic-multiply, 2 bits -> packed bf16 pair in ~4 VALU ops.
// +I handled in epilogue (acc + dinv_i * X_i), not in the bit expansion.
#define BM 64
#define BN 128
#define BK 64
#define LDT 68                 // padded LDS row stride (bf16): 136B
#define KTILES (NN / BK)

__global__ __launch_bounds__(256, 3) void k_gemm(
    const unsigned* __restrict__ mask32, const bf16_t* __restrict__ Xs_t,
    const bf16_t* __restrict__ X_bf,
    const float* __restrict__ dinv, bf16_t* __restrict__ H0)
{
  __shared__ bf16_t Ab[2][BM * LDT];
  __shared__ bf16_t Bb[2][BN * LDT];
  int v = blockIdx.z, rowblk = blockIdx.y, colblk = blockIdx.x;
  int t = threadIdx.x;
  int w = t >> 6, lane = t & 63;
  int fl = lane & 15, fh = lane >> 4;
  int wr = w >> 1, wc = w & 1;

  const unsigned* mrow = mask32 + ((size_t)v * NN + (size_t)rowblk * BM) * (NN / 32);
  const bf16_t* Bsrc = Xs_t + ((size_t)v * DD + (size_t)colblk * BN) * NN;

  int ar = t >> 2;                 // A-expansion: row 0..63
  int as = t & 3;                  // 16-elem segment
  int aw = as >> 1;                // which u32 word of the ktile
  int ah = (as & 1) * 16;          // bit half
  int brow = t >> 3;               // B staging: 0..31
  int bcol = (t & 7) * 8;

  f32x4 acc[2][4];
#pragma unroll
  for (int m = 0; m < 2; ++m)
#pragma unroll
    for (int n = 0; n < 4; ++n) { f32x4 z = {0.f, 0.f, 0.f, 0.f}; acc[m][n] = z; }

  bf16x8 br0, br1, br2, br3;
  unsigned mbits;

#define M_LOAD(kt_) do { mbits = mrow[(size_t)ar * (NN / 32) + (kt_) * 2 + aw]; } while (0)
#define B_LOAD(kt_) do { \
    const bf16_t* bq_ = Bsrc + (size_t)brow * NN + (size_t)(kt_) * BK + bcol; \
    br0 = *(const bf16x8*)(bq_); \
    br1 = *(const bf16x8*)(bq_ + (size_t)32 * NN); \
    br2 = *(const bf16x8*)(bq_ + (size_t)64 * NN); \
    br3 = *(const bf16x8*)(bq_ + (size_t)96 * NN); \
  } while (0)
#define B_WRITE(buf_) do { \
    bf16_t* bw_ = &Bb[buf_][brow * LDT + bcol]; \
    *(bf16x8*)(bw_) = br0; \
    *(bf16x8*)(bw_ + 32 * LDT) = br1; \
    *(bf16x8*)(bw_ + 64 * LDT) = br2; \
    *(bf16x8*)(bw_ + 96 * LDT) = br3; \
  } while (0)
// per nibble g: z = n4*0x8001 puts b0@bit0,b1@bit16 (after &0x10001);
// *0x3F80 turns each surviving bit into bf16 1.0 in the right half-word.
#define EXP_NIB(half_, g_, w0_, w1_) do { \
    unsigned n4_ = ((half_) >> ((g_) * 4)) & 0xFu; \
    unsigned z_ = n4_ * 0x8001u; \
    w0_ = (z_ & 0x10001u) * 0x3F80u; \
    w1_ = ((z_ >> 2) & 0x10001u) * 0x3F80u; \
  } while (0)
#define A_EXPAND(buf_) do { \
    unsigned half_ = (mbits >> ah) & 0xFFFFu; \
    unsigned a0_, a1_, a2_, a3_, a4_, a5_, a6_, a7_; \
    EXP_NIB(half_, 0, a0_, a1_); \
    EXP_NIB(half_, 1, a2_, a3_); \
    EXP_NIB(half_, 2, a4_, a5_); \
    EXP_NIB(half_, 3, a6_, a7_); \
    bf16_t* aw_ = &Ab[buf_][ar * LDT + as * 16]; \
    i32x4 q0_ = { (int)a0_, (int)a1_, (int)a2_, (int)a3_ }; \
    i32x4 q1_ = { (int)a4_, (int)a5_, (int)a6_, (int)a7_ }; \
    *(i32x4*)(aw_ + 0) = q0_; \
    *(i32x4*)(aw_ + 8) = q1_; \
  } while (0)

  M_LOAD(0); B_LOAD(0);
  A_EXPAND(0); B_WRITE(0);
  __syncthreads();
  int buf = 0;
  for (int kt = 0; kt < KTILES; ++kt) {
    if (kt + 1 < KTILES) { M_LOAD(kt + 1); B_LOAD(kt + 1); }
    {
      const bf16_t* Ap = &Ab[buf][(wr * 32) * LDT];
      const bf16_t* Bp = &Bb[buf][(wc * 64) * LDT];
#pragma unroll
      for (int ks = 0; ks < 2; ++ks) {
        const int ko = ks * 32 + fh * 8;
        bf16x8 af[2], bfr[4];
#pragma unroll
        for (int m = 0; m < 2; ++m) af[m] = *(const bf16x8*)(Ap + (m * 16 + fl) * LDT + ko);
#pragma unroll
        for (int n = 0; n < 4; ++n) bfr[n] = *(const bf16x8*)(Bp + (n * 16 + fl) * LDT + ko);
#pragma unroll
        for (int m = 0; m < 2; ++m)
#pragma unroll
          for (int n = 0; n < 4; ++n)
            acc[m][n] = MFMA16(af[m], bfr[n], acc[m][n], 0, 0, 0);
      }
    }
    if (kt + 1 < KTILES) { A_EXPAND(buf ^ 1); B_WRITE(buf ^ 1); }
    __syncthreads();
    buf ^= 1;
  }

  // epilogue: H0[i] = dinv_i * (acc_i + dinv_i * X_i)   (the +I term), bf16
  int gr0 = rowblk * BM + wr * 32;
  int gc0 = colblk * BN + wc * 64;
  bf16_t* Hv = H0 + (size_t)v * NN * DD;
  const bf16_t* Xv = X_bf + (size_t)v * NN * DD;
  const float* dv = dinv + v * NN;
#pragma unroll
  for (int m = 0; m < 2; ++m) {
    int rr = gr0 + m * 16 + fh * 4;
#pragma unroll
    for (int n = 0; n < 4; ++n) {
      int c = gc0 + n * 16 + fl;
      f32x4 a = acc[m][n];
#pragma unroll
      for (int g = 0; g < 4; ++g) {
        int r = rr + g;
        float d = dv[r];
        float x = bf2f(Xv[(size_t)r * DD + c]);
        Hv[(size_t)r * DD + c] = f2bf((a[g] + d * x) * d);
      }
    }
  }
}

// ---------------- K5: Ps = dinv .* (H0@Wc + bp) ; mlp = softplus(X@Wm + bm) -
__global__ __launch_bounds__(256) void k_small(
    const bf16_t* __restrict__ H0, const bf16_t* __restrict__ X_bf,
    const bf16_t* __restrict__ Wc_t, const bf16_t* __restrict__ Wm_t,
    const float* __restrict__ bp, const float* __restrict__ b_mlp,
    const float* __restrict__ dinv, float* __restrict__ Ps_g, float* __restrict__ mlp_g)
{
  __shared__ bf16_t Bc[16 * 520];
  __shared__ bf16_t Bm[16 * 520];
  int v = blockIdx.y;
  int t = threadIdx.x;
  {
    int r = t & 15, ch = t >> 4;
    const bf16_t* sc = Wc_t + (size_t)v * 16 * DD + (size_t)r * DD + ch * 32;
    const bf16_t* sm = Wm_t + (size_t)v * 16 * DD + (size_t)r * DD + ch * 32;
    bf16_t* dc = &Bc[r * 520 + ch * 32];
    bf16_t* dm = &Bm[r * 520 + ch * 32];
#pragma unroll
    for (int q = 0; q < 4; ++q) {
      *(bf16x8*)(dc + q * 8) = *(const bf16x8*)(sc + q * 8);
      *(bf16x8*)(dm + q * 8) = *(const bf16x8*)(sm + q * 8);
    }
  }
  __syncthreads();
  int w = t >> 6, lane = t & 63;
  int fl = lane & 15, fh = lane >> 4;
  int r0 = blockIdx.x * 64 + w * 16;
  const bf16_t* Arow = H0 + ((size_t)v * NN + r0 + fl) * DD;
  const bf16_t* Xrow = X_bf + ((size_t)v * NN + r0 + fl) * DD;
  f32x4 aP = {0.f, 0.f, 0.f, 0.f}, aM = {0.f, 0.f, 0.f, 0.f};
#pragma unroll
  for (int k = 0; k < 16; ++k) {
    bf16x8 a1 = *(const bf16x8*)(Arow + k * 32 + fh * 8);
    bf16x8 b1v = *(const bf16x8*)(&Bc[fl * 520 + k * 32 + fh * 8]);
    aP = MFMA16(a1, b1v, aP, 0, 0, 0);
    bf16x8 a2 = *(const bf16x8*)(Xrow + k * 32 + fh * 8);
    bf16x8 b2v = *(const bf16x8*)(&Bm[fl * 520 + k * 32 + fh * 8]);
    aM = MFMA16(a2, b2v, aM, 0, 0, 0);
  }
  if (fl < CC) {
    float bpv = bp[v * CC + fl];
    float bmv = b_mlp[v * CC + fl];
#pragma unroll
    for (int g = 0; g < 4; ++g) {
      int j = r0 + fh * 4 + g;
      float dj = dinv[v * NN + j];
      Ps_g[((size_t)v * CC + fl) * NN + j] = (aP[g] + bpv) * dj;
      mlp_g[((size_t)v * NN + j) * CC + fl] = splus(aM[g] + bmv);
    }
  }
}

// ---------------- K6: E = consensus + mlp + softplus(dinv_i*(Ahat@Ps) + b2) -
__global__ __launch_bounds__(256) void k_spmm(
    const unsigned long long* __restrict__ mask, const float* __restrict__ Ps_g,
    const float* __restrict__ mlp_g, const float* __restrict__ consensus,
    const float* __restrict__ b2, const float* __restrict__ dinv,
    float* __restrict__ E)
{
  __shared__ bf16_t PsL[CC * NN];   // 80 KB, [c][j]
  int v = blockIdx.y;
  int t = threadIdx.x;
  const float* Pv = Ps_g + (size_t)v * CC * NN;
  for (int q = 0; q < (CC * NN) / 256; ++q) {
    int idx = q * 256 + t;
    PsL[idx] = f2bf(Pv[idx]);
  }
  __syncthreads();
  int w = t >> 6, lane = t & 63;
  int i0 = blockIdx.x * 32 + w * 8;
  for (int rr = 0; rr < 8; ++rr) {
    int i = i0 + rr;
    unsigned long long bits = mask[((size_t)v * NN + i) * 64 + lane];
    float acc[CC];
#pragma unroll
    for (int c = 0; c < CC; ++c) acc[c] = 0.f;
    while (bits) {
      int b = __builtin_ctzll(bits);
      bits &= bits - 1;
      int j = lane * 64 + b;
#pragma unroll
      for (int c = 0; c < CC; ++c) acc[c] += bf2f(PsL[c * NN + j]);
    }
#pragma unroll
    for (int c = 0; c < CC; ++c) {
#pragma unroll
      for (int s = 32; s; s >>= 1) acc[c] += __shfl_xor(acc[c], s);
    }
    if (lane == 0) {
      float di = dinv[v * NN + i];
      const float* cons = consensus + ((size_t)v * NN + i) * CC;
      const float* ml = mlp_g + ((size_t)v * NN + i) * CC;
      float* Eo = E + ((size_t)v * NN + i) * CC;
#pragma unroll
      for (int c = 0; c < CC; ++c) {
        float s2 = acc[c] + bf2f(PsL[c * NN + i]);   // + I * Ps_i
        Eo[c] = cons[c] + ml[c] + splus(di * s2 + b2[v * CC + c]);
      }
    }
  }
}

// ---------------- K7a: per-block partial sums of pairwise cosine dots -------
__global__ __launch_bounds__(256) void k_sim(const float* __restrict__ E,
                                             float* __restrict__ partial)
{
  __shared__ float sm[3][256];
  int t = threadIdx.x;
  int n = blockIdx.x * 256 + t;
  float e0[CC], e1[CC], e2[CC];
#pragma unroll
  for (int c = 0; c < CC; ++c) {
    e0[c] = E[(size_t)(0 * NN + n) * CC + c];
    e1[c] = E[(size_t)(1 * NN + n) * CC + c];
    e2[c] = E[(size_t)(2 * NN + n) * CC + c];
  }
  float n0 = 0, n1 = 0, n2 = 0, d01 = 0, d02 = 0, d12 = 0;
#pragma unroll
  for (int c = 0; c < CC; ++c) { n0 += e0[c]*e0[c]; n1 += e1[c]*e1[c]; n2 += e2[c]*e2[c]; }
  float i0 = 1.0f / fmaxf(sqrtf(n0), 1e-8f);
  float i1 = 1.0f / fmaxf(sqrtf(n1), 1e-8f);
  float i2 = 1.0f / fmaxf(sqrtf(n2), 1e-8f);
#pragma unroll
  for (int c = 0; c < CC; ++c) { d01 += e0[c]*e1[c]; d02 += e0[c]*e2[c]; d12 += e1[c]*e2[c]; }
  sm[0][t] = d01 * i0 * i1;
  sm[1][t] = d02 * i0 * i2;
  sm[2][t] = d12 * i1 * i2;
  __syncthreads();
  for (int s = 128; s; s >>= 1) {
    if (t < s) { sm[0][t] += sm[0][t+s]; sm[1][t] += sm[1][t+s]; sm[2][t] += sm[2][t+s]; }
    __syncthreads();
  }
  if (t == 0) {
    partial[blockIdx.x * 3 + 0] = sm[0][0];
    partial[blockIdx.x * 3 + 1] = sm[1][0];
    partial[blockIdx.x * 3 + 2] = sm[2][0];
  }
}

// ---------------- K7b: S -> threshold -> row softmax -> coef[3] -------------
__global__ void k_coef(const float* __restrict__ partial, float* __restrict__ coef)
{
  if (threadIdx.x != 0) return;
  float S01 = 0, S02 = 0, S12 = 0;
  for (int b = 0; b < NN / 256; ++b) {
    S01 += partial[b * 3 + 0];
    S02 += partial[b * 3 + 1];
    S12 += partial[b * 3 + 2];
  }
  S01 /= (float)NN; S02 /= (float)NN; S12 /= (float)NN;
  float mx = fmaxf(S01, fmaxf(S02, S12));
  float thr = 0.7f * mx;
  float w01 = (S01 > thr) ? S01 : 0.f;
  float w02 = (S02 > thr) ? S02 : 0.f;
  float w12 = (S12 > thr) ? S12 : 0.f;
  float m0 = fmaxf(w01, w02);
  float e01 = expf(w01 - m0), e02 = expf(w02 - m0);
  float s0 = e01 + e02;
  float p01 = e01 / s0, p02 = e02 / s0;
  float p12 = 1.0f;
  (void)w12;
  coef[0] = (p01 + p02) / 6.0f;
  coef[1] = (p12 + p01) / 6.0f;
  coef[2] = (p02 + p12) / 6.0f;
}

// ---------------- K7c: agg[n,c] = sum_v coef[v] * E[v,n,c] ------------------
__global__ __launch_bounds__(256) void k_agg(const float* __restrict__ E,
    const float* __restrict__ coef, float* __restrict__ agg)
{
  int idx = blockIdx.x * 256 + threadIdx.x;
  float c0 = coef[0], c1 = coef[1], c2 = coef[2];
  agg[idx] = c0 * E[idx] + c1 * E[NN * CC + idx] + c2 * E[2 * NN * CC + idx];
}

// ---------------------------------------------------------------------------
extern "C" void kernel_launch(void* const* d_in, const int* in_sizes, int n_in,
                              void* d_out, int out_size, void* d_ws, size_t ws_size,
                              hipStream_t stream)
{
  (void)in_sizes; (void)n_in; (void)out_size;
  const float* X         = (const float*)d_in[0];
  const float* A         = (const float*)d_in[1];
  const float* consensus = (const float*)d_in[2];
  const float* W_mlp     = (const float*)d_in[3];
  const float* b_mlp     = (const float*)d_in[4];
  const float* W1        = (const float*)d_in[5];
  const float* b1        = (const float*)d_in[6];
  const float* W2        = (const float*)d_in[7];
  const float* b2        = (const float*)d_in[8];
  float* Eout = (float*)d_out;
  float* aggout = Eout + (size_t)VV * NN * CC;

  char* ws = (char*)d_ws;
  size_t off = 0;
  auto alloc = [&](size_t b) { char* p = ws + off; off += (b + 255) & ~(size_t)255; return p; };
  unsigned long long* mask = (unsigned long long*)alloc((size_t)VV * NN * 64 * 8);
  float*  dinv  = (float*) alloc((size_t)VV * NN * 4);
  bf16_t* Xs_t  = (bf16_t*)alloc((size_t)VV * DD * NN * 2);
  bf16_t* X_bf  = (bf16_t*)alloc((size_t)VV * NN * DD * 2);
  bf16_t* H0    = (bf16_t*)alloc((size_t)VV * NN * DD * 2);
  bf16_t* Wc_t  = (bf16_t*)alloc((size_t)VV * 16 * DD * 2);
  bf16_t* Wm_t  = (bf16_t*)alloc((size_t)VV * 16 * DD * 2);
  float*  bp    = (float*) alloc((size_t)VV * CC * 4);
  float*  Ps_g  = (float*) alloc((size_t)VV * CC * NN * 4);
  float*  mlp_g = (float*) alloc((size_t)VV * NN * CC * 4);
  float*  partial = (float*)alloc((NN / 256) * 3 * 4);
  float*  coef  = (float*) alloc(3 * 4);
  if (off > ws_size) return;

  k_mask <<<VV * NN / 4, 256, 0, stream>>>(A, mask, dinv);
  k_xpose<<<dim3(NN / 64, DD / 64, VV), 256, 0, stream>>>(X, dinv, Xs_t, X_bf);
  k_w    <<<391, 256, 0, stream>>>(W1, b1, W2, W_mlp, Wc_t, bp, Wm_t);
  k_gemm <<<dim3(DD / BN, NN / BM, VV), 256, 0, stream>>>((const unsigned*)mask, Xs_t, X_bf, dinv, H0);
  k_small<<<dim3(NN / 64, VV), 256, 0, stream>>>(H0, X_bf, Wc_t, Wm_t, bp, b_mlp, dinv, Ps_g, mlp_g);
  k_spmm <<<dim3(NN / 32, VV), 256, 0, stream>>>(mask, Ps_g, mlp_g, consensus, b2, dinv, Eout);
  k_sim  <<<NN / 256, 256, 0, stream>>>(Eout, partial);
  k_coef <<<1, 64, 0, stream>>>(partial, coef);
  k_agg  <<<NN * CC / 256, 256, 0, stream>>>(Eout, coef, aggout);
}

// Round 3
// 146.516 us; speedup vs baseline: 3.2177x; 3.2177x over previous
//
#include <hip/hip_runtime.h>
#include <stdint.h>
#include <stddef.h>

#define VV 3
#define NN 4096
#define DD 512
#define CC 10

typedef unsigned short bf16_t;
typedef __attribute__((ext_vector_type(8))) short bf16x8;
typedef __attribute__((ext_vector_type(4))) float f32x4;
typedef __attribute__((ext_vector_type(4))) unsigned short u16x4;

#define MFMA16 __builtin_amdgcn_mfma_f32_16x16x32_bf16

__device__ __forceinline__ float bf2f(bf16_t u) {
  union { unsigned u; float f; } c; c.u = ((unsigned)u) << 16; return c.f;
}
__device__ __forceinline__ bf16_t f2bf(float f) {
  union { float f; unsigned u; } c; c.f = f;
  unsigned r = (c.u + 0x7FFFu + ((c.u >> 16) & 1u)) >> 16;
  return (bf16_t)r;
}
__device__ __forceinline__ float splus(float x) {
  float ax = fabsf(x);
  return fmaxf(x, 0.0f) + log1pf(expf(-ax));
}

// ---------------- K1: blocks [0,3072): A -> bitmask + dinv ------------------
//                     blocks [3072,3456): X f32 -> X_bf bf16 cast -----------
__global__ __launch_bounds__(256) void k_mask(const float* __restrict__ A,
    const float* __restrict__ X,
    unsigned long long* __restrict__ mask, float* __restrict__ dinv,
    bf16_t* __restrict__ X_bf)
{
  if (blockIdx.x < VV * NN / 4) {
    int wid = blockIdx.x * 4 + (threadIdx.x >> 6);   // row id in [0, V*N)
    int lane = threadIdx.x & 63;
    const float* row = A + (size_t)wid * NN;
    unsigned long long myw = 0ull;
#pragma unroll 8
    for (int it = 0; it < 64; ++it) {
      float x = row[it * 64 + lane];
      unsigned long long b = __ballot(x != 0.0f);
      if (lane == it) myw = b;
    }
    mask[(size_t)wid * 64 + lane] = myw;
    int pc = __popcll(myw);
#pragma unroll
    for (int s = 32; s; s >>= 1) pc += __shfl_xor(pc, s);
    if (lane == 0) dinv[wid] = 1.0f / sqrtf((float)(pc + 1)); // deg = popcnt+1 (+I)
  } else {
    int blk = blockIdx.x - VV * NN / 4;               // 0..383
    const float4* src = (const float4*)X;
#pragma unroll
    for (int q = 0; q < 16; ++q) {
      int idx = blk * 4096 + q * 256 + threadIdx.x;   // float4 index
      float4 x = src[idx];
      u16x4 ob = { f2bf(x.x), f2bf(x.y), f2bf(x.z), f2bf(x.w) };
      *(u16x4*)(X_bf + (size_t)idx * 4) = ob;
    }
  }
}

// ---------------- K2: merged weight prep ------------------------------------
// blocks [0,385): Wc_t = (W1@W2)^T (bf16, padded to 16 rows), bp = b1@W2
// blocks [385,391): Wm_t = W_mlp^T (bf16, padded to 16 rows)
__global__ __launch_bounds__(256) void k_w(const float* __restrict__ W1,
    const float* __restrict__ b1, const float* __restrict__ W2,
    const float* __restrict__ W_mlp,
    bf16_t* __restrict__ Wc_t, float* __restrict__ bp, bf16_t* __restrict__ Wm_t)
{
  int t = threadIdx.x;
  if (blockIdx.x < 385) {
    int wid = blockIdx.x * 4 + (t >> 6);
    int lane = t & 63;
    if (wid >= VV * 513) return;
    int v = wid / 513, dd2 = wid % 513;
    const float* w2 = W2 + (size_t)v * DD * CC;
    const float* src = (dd2 < DD) ? (W1 + ((size_t)v * DD + dd2) * DD) : (b1 + (size_t)v * DD);
    float acc[CC];
#pragma unroll
    for (int c = 0; c < CC; ++c) acc[c] = 0.f;
    for (int it = 0; it < 8; ++it) {
      int e = it * 64 + lane;
      float w = src[e];
      const float* w2r = w2 + (size_t)e * CC;
#pragma unroll
      for (int c = 0; c < CC; ++c) acc[c] += w * w2r[c];
    }
#pragma unroll
    for (int c = 0; c < CC; ++c) {
#pragma unroll
      for (int s = 32; s; s >>= 1) acc[c] += __shfl_xor(acc[c], s);
    }
    if (lane == 0) {
      if (dd2 < DD) {
#pragma unroll
        for (int c = 0; c < CC; ++c) Wc_t[((size_t)v * 16 + c) * DD + dd2] = f2bf(acc[c]);
#pragma unroll
        for (int c = CC; c < 16; ++c) Wc_t[((size_t)v * 16 + c) * DD + dd2] = 0;
      } else {
#pragma unroll
        for (int c = 0; c < CC; ++c) bp[v * CC + c] = acc[c];
      }
    }
  } else {
    int idx = (blockIdx.x - 385) * 256 + t;
    if (idx >= VV * DD) return;
    int v = idx / DD, d = idx % DD;
#pragma unroll
    for (int c = 0; c < CC; ++c)
      Wm_t[((size_t)v * 16 + c) * DD + d] = f2bf(W_mlp[((size_t)v * DD + d) * CC + c]);
#pragma unroll
    for (int c = CC; c < 16; ++c) Wm_t[((size_t)v * 16 + c) * DD + d] = 0;
  }
}

// ---------------- K3: Ps1[v,c,j] = dinv_j * (X[v,j,:]·Wc[:,c]) --------------
//                      mlp[v,j,c] = softplus(X·Wm + bm)        (MFMA, C=10)
__global__ __launch_bounds__(256) void k_zs(
    const bf16_t* __restrict__ X_bf,
    const bf16_t* __restrict__ Wc_t, const bf16_t* __restrict__ Wm_t,
    const float* __restrict__ b_mlp, const float* __restrict__ dinv,
    float* __restrict__ Ps1_g, float* __restrict__ mlp_g)
{
  __shared__ bf16_t Bc[16 * 520];
  __shared__ bf16_t Bm[16 * 520];
  int v = blockIdx.y;
  int t = threadIdx.x;
  {
    int r = t & 15, ch = t >> 4;
    const bf16_t* sc = Wc_t + (size_t)v * 16 * DD + (size_t)r * DD + ch * 32;
    const bf16_t* sm = Wm_t + (size_t)v * 16 * DD + (size_t)r * DD + ch * 32;
    bf16_t* dc = &Bc[r * 520 + ch * 32];
    bf16_t* dm = &Bm[r * 520 + ch * 32];
#pragma unroll
    for (int q = 0; q < 4; ++q) {
      *(bf16x8*)(dc + q * 8) = *(const bf16x8*)(sc + q * 8);
      *(bf16x8*)(dm + q * 8) = *(const bf16x8*)(sm + q * 8);
    }
  }
  __syncthreads();
  int w = t >> 6, lane = t & 63;
  int fl = lane & 15, fh = lane >> 4;
  int r0 = blockIdx.x * 64 + w * 16;
  const bf16_t* Xrow = X_bf + ((size_t)v * NN + r0 + fl) * DD;
  f32x4 aP = {0.f, 0.f, 0.f, 0.f}, aM = {0.f, 0.f, 0.f, 0.f};
#pragma unroll
  for (int k = 0; k < 16; ++k) {
    bf16x8 a = *(const bf16x8*)(Xrow + k * 32 + fh * 8);
    bf16x8 b1v = *(const bf16x8*)(&Bc[fl * 520 + k * 32 + fh * 8]);
    aP = MFMA16(a, b1v, aP, 0, 0, 0);
    bf16x8 b2v = *(const bf16x8*)(&Bm[fl * 520 + k * 32 + fh * 8]);
    aM = MFMA16(a, b2v, aM, 0, 0, 0);
  }
  if (fl < CC) {
    float bmv = b_mlp[v * CC + fl];
#pragma unroll
    for (int g = 0; g < 4; ++g) {
      int j = r0 + fh * 4 + g;
      float dj = dinv[v * NN + j];
      Ps1_g[((size_t)v * CC + fl) * NN + j] = aP[g] * dj;
      mlp_g[((size_t)v * NN + j) * CC + fl] = splus(aM[g] + bmv);
    }
  }
}

// ---------------- K4: pass1  P2[c,j] = dinv_j*(dinv_j*(Ahat@Ps1)[j,c] + bp_c)
__global__ __launch_bounds__(256) void k_spmm1(
    const unsigned long long* __restrict__ mask, const float* __restrict__ Ps1_g,
    const float* __restrict__ bp, const float* __restrict__ dinv,
    float* __restrict__ P2_g)
{
  __shared__ bf16_t PsL[CC * NN];   // 80 KB, [c][j]
  int v = blockIdx.y;
  int t = threadIdx.x;
  const float* Pv = Ps1_g + (size_t)v * CC * NN;
  for (int q = 0; q < (CC * NN) / 256; ++q) {
    int idx = q * 256 + t;
    PsL[idx] = f2bf(Pv[idx]);
  }
  __syncthreads();
  int w = t >> 6, lane = t & 63;
  int i0 = blockIdx.x * 32 + w * 8;
  for (int rr = 0; rr < 8; ++rr) {
    int i = i0 + rr;
    unsigned long long bits = mask[((size_t)v * NN + i) * 64 + lane];
    float acc[CC];
#pragma unroll
    for (int c = 0; c < CC; ++c) acc[c] = 0.f;
    while (bits) {
      int b = __builtin_ctzll(bits);
      bits &= bits - 1;
      int j = lane * 64 + b;
#pragma unroll
      for (int c = 0; c < CC; ++c) acc[c] += bf2f(PsL[c * NN + j]);
    }
#pragma unroll
    for (int c = 0; c < CC; ++c) {
#pragma unroll
      for (int s = 32; s; s >>= 1) acc[c] += __shfl_xor(acc[c], s);
    }
    if (lane == 0) {
      float di = dinv[v * NN + i];
#pragma unroll
      for (int c = 0; c < CC; ++c) {
        float s2 = acc[c] + bf2f(PsL[c * NN + i]);   // + self (the +I)
        P2_g[((size_t)v * CC + c) * NN + i] = di * (di * s2 + bp[v * CC + c]);
      }
    }
  }
}

// ---------------- K5: pass2  E = consensus + mlp + softplus(dinv*(Ahat@P2)+b2)
__global__ __launch_bounds__(256) void k_spmm2(
    const unsigned long long* __restrict__ mask, const float* __restrict__ P2_g,
    const float* __restrict__ mlp_g, const float* __restrict__ consensus,
    const float* __restrict__ b2, const float* __restrict__ dinv,
    float* __restrict__ E)
{
  __shared__ bf16_t PsL[CC * NN];   // 80 KB, [c][j]
  int v = blockIdx.y;
  int t = threadIdx.x;
  const float* Pv = P2_g + (size_t)v * CC * NN;
  for (int q = 0; q < (CC * NN) / 256; ++q) {
    int idx = q * 256 + t;
    PsL[idx] = f2bf(Pv[idx]);
  }
  __syncthreads();
  int w = t >> 6, lane = t & 63;
  int i0 = blockIdx.x * 32 + w * 8;
  for (int rr = 0; rr < 8; ++rr) {
    int i = i0 + rr;
    unsigned long long bits = mask[((size_t)v * NN + i) * 64 + lane];
    float acc[CC];
#pragma unroll
    for (int c = 0; c < CC; ++c) acc[c] = 0.f;
    while (bits) {
      int b = __builtin_ctzll(bits);
      bits &= bits - 1;
      int j = lane * 64 + b;
#pragma unroll
      for (int c = 0; c < CC; ++c) acc[c] += bf2f(PsL[c * NN + j]);
    }
#pragma unroll
    for (int c = 0; c < CC; ++c) {
#pragma unroll
      for (int s = 32; s; s >>= 1) acc[c] += __shfl_xor(acc[c], s);
    }
    if (lane == 0) {
      float di = dinv[v * NN + i];
      const float* cons = consensus + ((size_t)v * NN + i) * CC;
      const float* ml = mlp_g + ((size_t)v * NN + i) * CC;
      float* Eo = E + ((size_t)v * NN + i) * CC;
#pragma unroll
      for (int c = 0; c < CC; ++c) {
        float s2 = acc[c] + bf2f(PsL[c * NN + i]);   // + self (the +I)
        Eo[c] = cons[c] + ml[c] + splus(di * s2 + b2[v * CC + c]);
      }
    }
  }
}

// ---------------- K6a: per-block partial sums of pairwise cosine dots -------
__global__ __launch_bounds__(256) void k_sim(const float* __restrict__ E,
                                             float* __restrict__ partial)
{
  __shared__ float sm[3][256];
  int t = threadIdx.x;
  int n = blockIdx.x * 256 + t;
  float e0[CC], e1[CC], e2[CC];
#pragma unroll
  for (int c = 0; c < CC; ++c) {
    e0[c] = E[(size_t)(0 * NN + n) * CC + c];
    e1[c] = E[(size_t)(1 * NN + n) * CC + c];
    e2[c] = E[(size_t)(2 * NN + n) * CC + c];
  }
  float n0 = 0, n1 = 0, n2 = 0, d01 = 0, d02 = 0, d12 = 0;
#pragma unroll
  for (int c = 0; c < CC; ++c) { n0 += e0[c]*e0[c]; n1 += e1[c]*e1[c]; n2 += e2[c]*e2[c]; }
  float i0 = 1.0f / fmaxf(sqrtf(n0), 1e-8f);
  float i1 = 1.0f / fmaxf(sqrtf(n1), 1e-8f);
  float i2 = 1.0f / fmaxf(sqrtf(n2), 1e-8f);
#pragma unroll
  for (int c = 0; c < CC; ++c) { d01 += e0[c]*e1[c]; d02 += e0[c]*e2[c]; d12 += e1[c]*e2[c]; }
  sm[0][t] = d01 * i0 * i1;
  sm[1][t] = d02 * i0 * i2;
  sm[2][t] = d12 * i1 * i2;
  __syncthreads();
  for (int s = 128; s; s >>= 1) {
    if (t < s) { sm[0][t] += sm[0][t+s]; sm[1][t] += sm[1][t+s]; sm[2][t] += sm[2][t+s]; }
    __syncthreads();
  }
  if (t == 0) {
    partial[blockIdx.x * 3 + 0] = sm[0][0];
    partial[blockIdx.x * 3 + 1] = sm[1][0];
    partial[blockIdx.x * 3 + 2] = sm[2][0];
  }
}

// ---------------- K6b: S -> threshold -> row softmax -> coef[3] -------------
__global__ void k_coef(const float* __restrict__ partial, float* __restrict__ coef)
{
  if (threadIdx.x != 0) return;
  float S01 = 0, S02 = 0, S12 = 0;
  for (int b = 0; b < NN / 256; ++b) {
    S01 += partial[b * 3 + 0];
    S02 += partial[b * 3 + 1];
    S12 += partial[b * 3 + 2];
  }
  S01 /= (float)NN; S02 /= (float)NN; S12 /= (float)NN;
  float mx = fmaxf(S01, fmaxf(S02, S12));
  float thr = 0.7f * mx;
  float w01 = (S01 > thr) ? S01 : 0.f;
  float w02 = (S02 > thr) ? S02 : 0.f;
  float w12 = (S12 > thr) ? S12 : 0.f;
  float m0 = fmaxf(w01, w02);
  float e01 = expf(w01 - m0), e02 = expf(w02 - m0);
  float s0 = e01 + e02;
  float p01 = e01 / s0, p02 = e02 / s0;
  float p12 = 1.0f;
  (void)w12;
  coef[0] = (p01 + p02) / 6.0f;
  coef[1] = (p12 + p01) / 6.0f;
  coef[2] = (p02 + p12) / 6.0f;
}

// ---------------- K6c: agg[n,c] = sum_v coef[v] * E[v,n,c] ------------------
__global__ __launch_bounds__(256) void k_agg(const float* __restrict__ E,
    const float* __restrict__ coef, float* __restrict__ agg)
{
  int idx = blockIdx.x * 256 + threadIdx.x;
  float c0 = coef[0], c1 = coef[1], c2 = coef[2];
  agg[idx] = c0 * E[idx] + c1 * E[NN * CC + idx] + c2 * E[2 * NN * CC + idx];
}

// ---------------------------------------------------------------------------
extern "C" void kernel_launch(void* const* d_in, const int* in_sizes, int n_in,
                              void* d_out, int out_size, void* d_ws, size_t ws_size,
                              hipStream_t stream)
{
  (void)in_sizes; (void)n_in; (void)out_size;
  const float* X         = (const float*)d_in[0];
  const float* A         = (const float*)d_in[1];
  const float* consensus = (const float*)d_in[2];
  const float* W_mlp     = (const float*)d_in[3];
  const float* b_mlp     = (const float*)d_in[4];
  const float* W1        = (const float*)d_in[5];
  const float* b1        = (const float*)d_in[6];
  const float* W2        = (const float*)d_in[7];
  const float* b2        = (const float*)d_in[8];
  float* Eout = (float*)d_out;
  float* aggout = Eout + (size_t)VV * NN * CC;

  char* ws = (char*)d_ws;
  size_t off = 0;
  auto alloc = [&](size_t b) { char* p = ws + off; off += (b + 255) & ~(size_t)255; return p; };
  unsigned long long* mask = (unsigned long long*)alloc((size_t)VV * NN * 64 * 8);
  float*  dinv  = (float*) alloc((size_t)VV * NN * 4);
  bf16_t* X_bf  = (bf16_t*)alloc((size_t)VV * NN * DD * 2);
  bf16_t* Wc_t  = (bf16_t*)alloc((size_t)VV * 16 * DD * 2);
  bf16_t* Wm_t  = (bf16_t*)alloc((size_t)VV * 16 * DD * 2);
  float*  bp    = (float*) alloc((size_t)VV * CC * 4);
  float*  Ps1_g = (float*) alloc((size_t)VV * CC * NN * 4);
  float*  P2_g  = (float*) alloc((size_t)VV * CC * NN * 4);
  float*  mlp_g = (float*) alloc((size_t)VV * NN * CC * 4);
  float*  partial = (float*)alloc((NN / 256) * 3 * 4);
  float*  coef  = (float*) alloc(3 * 4);
  if (off > ws_size) return;

  k_mask <<<VV * NN / 4 + 384, 256, 0, stream>>>(A, X, mask, dinv, X_bf);
  k_w    <<<391, 256, 0, stream>>>(W1, b1, W2, W_mlp, Wc_t, bp, Wm_t);
  k_zs   <<<dim3(NN / 64, VV), 256, 0, stream>>>(X_bf, Wc_t, Wm_t, b_mlp, dinv, Ps1_g, mlp_g);
  k_spmm1<<<dim3(NN / 32, VV), 256, 0, stream>>>(mask, Ps1_g, bp, dinv, P2_g);
  k_spmm2<<<dim3(NN / 32, VV), 256, 0, stream>>>(mask, P2_g, mlp_g, consensus, b2, dinv, Eout);
  k_sim  <<<NN / 256, 256, 0, stream>>>(Eout, partial);
  k_coef <<<1, 64, 0, stream>>>(partial, coef);
  k_agg  <<<NN * CC / 256, 256, 0, stream>>>(Eout, coef, aggout);
}

// Round 4
// 82.553 us; speedup vs baseline: 5.7108x; 1.7748x over previous
//
#include <hip/hip_runtime.h>
#include <stdint.h>
#include <stddef.h>

#define VV 3
#define NN 4096
#define DD 512
#define CC 10

typedef unsigned short bf16_t;
typedef __attribute__((ext_vector_type(8))) short bf16x8;
typedef __attribute__((ext_vector_type(4))) float f32x4;

#define MFMA16 __builtin_amdgcn_mfma_f32_16x16x32_bf16

__device__ __forceinline__ float bf2f(unsigned u) {
  union { unsigned u; float f; } c; c.u = u << 16; return c.f;
}
__device__ __forceinline__ bf16_t f2bf(float f) {
  union { float f; unsigned u; } c; c.f = f;
  unsigned r = (c.u + 0x7FFFu + ((c.u >> 16) & 1u)) >> 16;
  return (bf16_t)r;
}
__device__ __forceinline__ float splus(float x) {
  float ax = fabsf(x);
  return fmaxf(x, 0.0f) + log1pf(expf(-ax));
}

// ---------------- K1: fused prep -------------------------------------------
// blocks [0,3072):        A -> bitmask + dinv = 1/sqrt(deg)
// blocks [3072,3457):     Wc_t = (W1@W2)^T bf16 (padded 16 rows), bp = b1@W2
// blocks [3457,3463):     Wm_t = W_mlp^T bf16 (padded 16 rows)
__global__ __launch_bounds__(256) void k_prep(const float* __restrict__ A,
    const float* __restrict__ W1, const float* __restrict__ b1,
    const float* __restrict__ W2, const float* __restrict__ W_mlp,
    unsigned long long* __restrict__ mask, float* __restrict__ dinv,
    bf16_t* __restrict__ Wc_t, float* __restrict__ bp, bf16_t* __restrict__ Wm_t)
{
  int t = threadIdx.x;
  if (blockIdx.x < VV * NN / 4) {
    int wid = blockIdx.x * 4 + (t >> 6);             // row id in [0, V*N)
    int lane = t & 63;
    const float* row = A + (size_t)wid * NN;
    unsigned long long myw = 0ull;
#pragma unroll 8
    for (int it = 0; it < 64; ++it) {
      float x = row[it * 64 + lane];
      unsigned long long b = __ballot(x != 0.0f);
      if (lane == it) myw = b;
    }
    mask[(size_t)wid * 64 + lane] = myw;
    int pc = __popcll(myw);
#pragma unroll
    for (int s = 32; s; s >>= 1) pc += __shfl_xor(pc, s);
    if (lane == 0) dinv[wid] = 1.0f / sqrtf((float)(pc + 1)); // deg = popcnt+1 (+I)
  } else if (blockIdx.x < VV * NN / 4 + 385) {
    int blk = blockIdx.x - VV * NN / 4;
    int wid = blk * 4 + (t >> 6);
    int lane = t & 63;
    if (wid >= VV * 513) return;
    int v = wid / 513, dd2 = wid % 513;
    const float* w2 = W2 + (size_t)v * DD * CC;
    const float* src = (dd2 < DD) ? (W1 + ((size_t)v * DD + dd2) * DD) : (b1 + (size_t)v * DD);
    float acc[CC];
#pragma unroll
    for (int c = 0; c < CC; ++c) acc[c] = 0.f;
    for (int it = 0; it < 8; ++it) {
      int e = it * 64 + lane;
      float w = src[e];
      const float* w2r = w2 + (size_t)e * CC;
#pragma unroll
      for (int c = 0; c < CC; ++c) acc[c] += w * w2r[c];
    }
#pragma unroll
    for (int c = 0; c < CC; ++c) {
#pragma unroll
      for (int s = 32; s; s >>= 1) acc[c] += __shfl_xor(acc[c], s);
    }
    if (lane == 0) {
      if (dd2 < DD) {
#pragma unroll
        for (int c = 0; c < CC; ++c) Wc_t[((size_t)v * 16 + c) * DD + dd2] = f2bf(acc[c]);
#pragma unroll
        for (int c = CC; c < 16; ++c) Wc_t[((size_t)v * 16 + c) * DD + dd2] = 0;
      } else {
#pragma unroll
        for (int c = 0; c < CC; ++c) bp[v * CC + c] = acc[c];
      }
    }
  } else {
    int idx = (blockIdx.x - (VV * NN / 4 + 385)) * 256 + t;
    if (idx >= VV * DD) return;
    int v = idx / DD, d = idx % DD;
#pragma unroll
    for (int c = 0; c < CC; ++c)
      Wm_t[((size_t)v * 16 + c) * DD + d] = f2bf(W_mlp[((size_t)v * DD + d) * CC + c]);
#pragma unroll
    for (int c = CC; c < 16; ++c) Wm_t[((size_t)v * 16 + c) * DD + d] = 0;
  }
}

// ---------------- K2: Ps1p[v][c/2][j] = packed bf16 pair of dinv_j*(X·Wc) ---
//                      Epart[v,j,c] = consensus + softplus(X·Wm + bm)
// X read directly as f32 (sole consumer), converted in-register for MFMA.
__global__ __launch_bounds__(256) void k_zs(
    const float* __restrict__ X,
    const bf16_t* __restrict__ Wc_t, const bf16_t* __restrict__ Wm_t,
    const float* __restrict__ b_mlp, const float* __restrict__ consensus,
    const float* __restrict__ dinv,
    unsigned* __restrict__ Ps1p, float* __restrict__ Epart)
{
  __shared__ bf16_t Bc[16 * 520];
  __shared__ bf16_t Bm[16 * 520];
  int v = blockIdx.y;
  int t = threadIdx.x;
  {
    int r = t & 15, ch = t >> 4;
    const bf16_t* sc = Wc_t + (size_t)v * 16 * DD + (size_t)r * DD + ch * 32;
    const bf16_t* sm = Wm_t + (size_t)v * 16 * DD + (size_t)r * DD + ch * 32;
    bf16_t* dc = &Bc[r * 520 + ch * 32];
    bf16_t* dm = &Bm[r * 520 + ch * 32];
#pragma unroll
    for (int q = 0; q < 4; ++q) {
      *(bf16x8*)(dc + q * 8) = *(const bf16x8*)(sc + q * 8);
      *(bf16x8*)(dm + q * 8) = *(const bf16x8*)(sm + q * 8);
    }
  }
  __syncthreads();
  int w = t >> 6, lane = t & 63;
  int fl = lane & 15, fh = lane >> 4;
  int r0 = blockIdx.x * 64 + w * 16;
  const float* Xrow = X + ((size_t)v * NN + r0 + fl) * DD;
  f32x4 aP = {0.f, 0.f, 0.f, 0.f}, aM = {0.f, 0.f, 0.f, 0.f};
#pragma unroll
  for (int k = 0; k < 16; ++k) {
    float4 x0 = *(const float4*)(Xrow + k * 32 + fh * 8);
    float4 x1 = *(const float4*)(Xrow + k * 32 + fh * 8 + 4);
    bf16x8 a = { (short)f2bf(x0.x), (short)f2bf(x0.y), (short)f2bf(x0.z), (short)f2bf(x0.w),
                 (short)f2bf(x1.x), (short)f2bf(x1.y), (short)f2bf(x1.z), (short)f2bf(x1.w) };
    bf16x8 b1v = *(const bf16x8*)(&Bc[fl * 520 + k * 32 + fh * 8]);
    aP = MFMA16(a, b1v, aP, 0, 0, 0);
    bf16x8 b2v = *(const bf16x8*)(&Bm[fl * 520 + k * 32 + fh * 8]);
    aM = MFMA16(a, b2v, aM, 0, 0, 0);
  }
  float bmv = (fl < CC) ? b_mlp[v * CC + fl] : 0.f;
#pragma unroll
  for (int g = 0; g < 4; ++g) {
    int j = r0 + fh * 4 + g;
    float dj = dinv[v * NN + j];
    float val = aP[g] * dj;
    float part = __shfl_xor(val, 1);            // partner channel fl^1, same j
    if (((fl & 1) == 0) && fl < CC) {
      unsigned pw = (unsigned)f2bf(val) | ((unsigned)f2bf(part) << 16);
      Ps1p[((size_t)v * 5 + (fl >> 1)) * NN + j] = pw;
    }
    if (fl < CC) {
      size_t ad = ((size_t)v * NN + j) * CC + fl;
      Epart[ad] = consensus[ad] + splus(aM[g] + bmv);
    }
  }
}

// ---- shared gather core: 8-lane group per row, bf16-pair packed LDS panel --
#define SPMM_PROLOG(SRC_) \
  __shared__ unsigned PsL[5 * NN];  /* 80 KB */ \
  int v = blockIdx.y; \
  int t = threadIdx.x; \
  { \
    const uint4* src_ = (const uint4*)((SRC_) + (size_t)v * 5 * NN); \
    uint4* dst_ = (uint4*)PsL; \
    _Pragma("unroll") \
    for (int q = 0; q < 20; ++q) dst_[q * 256 + t] = src_[q * 256 + t]; \
  } \
  __syncthreads(); \
  int w = t >> 6, g = (t >> 3) & 7, s = t & 7; \
  int i = blockIdx.x * 32 + w * 8 + g; \
  const unsigned long long* mrow = mask + ((size_t)v * NN + i) * 64; \
  float acc[CC]; \
  _Pragma("unroll") \
  for (int c = 0; c < CC; ++c) acc[c] = 0.f; \
  _Pragma("unroll") \
  for (int it = 0; it < 8; ++it) { \
    unsigned long long bits = mrow[it * 8 + s]; \
    int jb = (it * 8 + s) * 64; \
    while (bits) { \
      int b = __builtin_ctzll(bits); \
      bits &= bits - 1; \
      int j = jb + b; \
      _Pragma("unroll") \
      for (int c2 = 0; c2 < 5; ++c2) { \
        unsigned pw = PsL[c2 * NN + j]; \
        acc[2 * c2]     += bf2f(pw & 0xFFFFu); \
        acc[2 * c2 + 1] += bf2f(pw >> 16); \
      } \
    } \
  } \
  _Pragma("unroll") \
  for (int c = 0; c < CC; ++c) { \
    acc[c] += __shfl_xor(acc[c], 1); \
    acc[c] += __shfl_xor(acc[c], 2); \
    acc[c] += __shfl_xor(acc[c], 4); \
  }

// ---------------- K3: P2p[c/2][i] = pack(di*(di*(Ahat@Ps1)[i,c] + bp_c)) ----
__global__ __launch_bounds__(256) void k_spmm1(
    const unsigned long long* __restrict__ mask, const unsigned* __restrict__ Ps1p,
    const float* __restrict__ bp, const float* __restrict__ dinv,
    unsigned* __restrict__ P2p)
{
  SPMM_PROLOG(Ps1p)
  if (s == 0) {
    float di = dinv[v * NN + i];
#pragma unroll
    for (int c2 = 0; c2 < 5; ++c2) {             // + self (the +I)
      unsigned pw = PsL[c2 * NN + i];
      acc[2 * c2]     += bf2f(pw & 0xFFFFu);
      acc[2 * c2 + 1] += bf2f(pw >> 16);
    }
#pragma unroll
    for (int c2 = 0; c2 < 5; ++c2) {
      float lo = di * (di * acc[2 * c2]     + bp[v * CC + 2 * c2]);
      float hi = di * (di * acc[2 * c2 + 1] + bp[v * CC + 2 * c2 + 1]);
      P2p[((size_t)v * 5 + c2) * NN + i] = (unsigned)f2bf(lo) | ((unsigned)f2bf(hi) << 16);
    }
  }
}

// ---------------- K4: E += softplus(di*(Ahat@P2) + b2)  (in place on Epart) -
__global__ __launch_bounds__(256) void k_spmm2(
    const unsigned long long* __restrict__ mask, const unsigned* __restrict__ P2p,
    const float* __restrict__ b2, const float* __restrict__ dinv,
    float* __restrict__ E)
{
  SPMM_PROLOG(P2p)
  if (s == 0) {
    float di = dinv[v * NN + i];
#pragma unroll
    for (int c2 = 0; c2 < 5; ++c2) {             // + self (the +I)
      unsigned pw = PsL[c2 * NN + i];
      acc[2 * c2]     += bf2f(pw & 0xFFFFu);
      acc[2 * c2 + 1] += bf2f(pw >> 16);
    }
    float* Eo = E + ((size_t)v * NN + i) * CC;
#pragma unroll
    for (int c = 0; c < CC; ++c)
      Eo[c] = Eo[c] + splus(di * acc[c] + b2[v * CC + c]);
  }
}

// ---------------- K5: per-block partial sums of pairwise cosine dots --------
__global__ __launch_bounds__(256) void k_sim(const float* __restrict__ E,
                                             float* __restrict__ partial)
{
  __shared__ float sm[3][256];
  int t = threadIdx.x;
  int n = blockIdx.x * 256 + t;
  float e0[CC], e1[CC], e2[CC];
#pragma unroll
  for (int c = 0; c < CC; ++c) {
    e0[c] = E[(size_t)(0 * NN + n) * CC + c];
    e1[c] = E[(size_t)(1 * NN + n) * CC + c];
    e2[c] = E[(size_t)(2 * NN + n) * CC + c];
  }
  float n0 = 0, n1 = 0, n2 = 0, d01 = 0, d02 = 0, d12 = 0;
#pragma unroll
  for (int c = 0; c < CC; ++c) { n0 += e0[c]*e0[c]; n1 += e1[c]*e1[c]; n2 += e2[c]*e2[c]; }
  float i0 = 1.0f / fmaxf(sqrtf(n0), 1e-8f);
  float i1 = 1.0f / fmaxf(sqrtf(n1), 1e-8f);
  float i2 = 1.0f / fmaxf(sqrtf(n2), 1e-8f);
#pragma unroll
  for (int c = 0; c < CC; ++c) { d01 += e0[c]*e1[c]; d02 += e0[c]*e2[c]; d12 += e1[c]*e2[c]; }
  sm[0][t] = d01 * i0 * i1;
  sm[1][t] = d02 * i0 * i2;
  sm[2][t] = d12 * i1 * i2;
  __syncthreads();
  for (int s = 128; s; s >>= 1) {
    if (t < s) { sm[0][t] += sm[0][t+s]; sm[1][t] += sm[1][t+s]; sm[2][t] += sm[2][t+s]; }
    __syncthreads();
  }
  if (t == 0) {
    partial[blockIdx.x * 3 + 0] = sm[0][0];
    partial[blockIdx.x * 3 + 1] = sm[1][0];
    partial[blockIdx.x * 3 + 2] = sm[2][0];
  }
}

// ---------------- K6: coef (redundant per block) + agg ----------------------
__global__ __launch_bounds__(256) void k_aggc(const float* __restrict__ E,
    const float* __restrict__ partial, float* __restrict__ agg)
{
  float S01 = 0, S02 = 0, S12 = 0;
  for (int b = 0; b < NN / 256; ++b) {
    S01 += partial[b * 3 + 0];
    S02 += partial[b * 3 + 1];
    S12 += partial[b * 3 + 2];
  }
  S01 /= (float)NN; S02 /= (float)NN; S12 /= (float)NN;
  float mx = fmaxf(S01, fmaxf(S02, S12));
  float thr = 0.7f * mx;
  float w01 = (S01 > thr) ? S01 : 0.f;
  float w02 = (S02 > thr) ? S02 : 0.f;
  float m0 = fmaxf(w01, w02);
  float e01 = expf(w01 - m0), e02 = expf(w02 - m0);
  float s0 = e01 + e02;
  float p01 = e01 / s0, p02 = e02 / s0;
  float p12 = 1.0f;                      // row-1 softmax over its single edge
  float c0 = (p01 + p02) / 6.0f;
  float c1 = (p12 + p01) / 6.0f;
  float c2 = (p02 + p12) / 6.0f;
  int idx = blockIdx.x * 256 + threadIdx.x;
  agg[idx] = c0 * E[idx] + c1 * E[NN * CC + idx] + c2 * E[2 * NN * CC + idx];
}

// ---------------------------------------------------------------------------
extern "C" void kernel_launch(void* const* d_in, const int* in_sizes, int n_in,
                              void* d_out, int out_size, void* d_ws, size_t ws_size,
                              hipStream_t stream)
{
  (void)in_sizes; (void)n_in; (void)out_size;
  const float* X         = (const float*)d_in[0];
  const float* A         = (const float*)d_in[1];
  const float* consensus = (const float*)d_in[2];
  const float* W_mlp     = (const float*)d_in[3];
  const float* b_mlp     = (const float*)d_in[4];
  const float* W1        = (const float*)d_in[5];
  const float* b1        = (const float*)d_in[6];
  const float* W2        = (const float*)d_in[7];
  const float* b2        = (const float*)d_in[8];
  float* Eout = (float*)d_out;
  float* aggout = Eout + (size_t)VV * NN * CC;

  char* ws = (char*)d_ws;
  size_t off = 0;
  auto alloc = [&](size_t b) { char* p = ws + off; off += (b + 255) & ~(size_t)255; return p; };
  unsigned long long* mask = (unsigned long long*)alloc((size_t)VV * NN * 64 * 8);
  float*  dinv  = (float*) alloc((size_t)VV * NN * 4);
  bf16_t* Wc_t  = (bf16_t*)alloc((size_t)VV * 16 * DD * 2);
  bf16_t* Wm_t  = (bf16_t*)alloc((size_t)VV * 16 * DD * 2);
  float*  bp    = (float*) alloc((size_t)VV * CC * 4);
  unsigned* Ps1p = (unsigned*)alloc((size_t)VV * 5 * NN * 4);
  unsigned* P2p  = (unsigned*)alloc((size_t)VV * 5 * NN * 4);
  float*  partial = (float*)alloc((NN / 256) * 3 * 4);
  if (off > ws_size) return;

  k_prep <<<VV * NN / 4 + 385 + 6, 256, 0, stream>>>(A, W1, b1, W2, W_mlp,
                                                     mask, dinv, Wc_t, bp, Wm_t);
  k_zs   <<<dim3(NN / 64, VV), 256, 0, stream>>>(X, Wc_t, Wm_t, b_mlp, consensus,
                                                 dinv, Ps1p, Eout);
  k_spmm1<<<dim3(NN / 32, VV), 256, 0, stream>>>(mask, Ps1p, bp, dinv, P2p);
  k_spmm2<<<dim3(NN / 32, VV), 256, 0, stream>>>(mask, P2p, b2, dinv, Eout);
  k_sim  <<<NN / 256, 256, 0, stream>>>(Eout, partial);
  k_aggc <<<NN * CC / 256, 256, 0, stream>>>(Eout, partial, aggout);
}